// Round 1
// baseline (1002.096 us; speedup 1.0000x reference)
//
#include <hip/hip_runtime.h>
#include <math.h>

#define B_ 4
#define N_ 5000
#define K_ 16
#define L_ 3
#define F_ 2
#define E_ 32
#define D_ 64
#define H_ 4
#define BN_ (B_*N_)          /* 20000 */
#define NK_ (N_*K_)          /* 80000 */
#define BIG_ 1.0e9f

// ---------------- zero the accumulators -------------------------------------
__global__ void k_zero(float* __restrict__ acc) {
    if (threadIdx.x < 16) acc[threadIdx.x] = 0.f;
}

// ---------------- encoder: h = [emb_norm, feat] @ enc_W + enc_b -------------
// one wave per node, lane d computes h[d]
__global__ __launch_bounds__(256) void k_encode(
    const float* __restrict__ embed, const float* __restrict__ feat,
    const float* __restrict__ encW, const float* __restrict__ encb,
    float* __restrict__ h)
{
    int wave = threadIdx.x >> 6;
    int lane = threadIdx.x & 63;
    int node = blockIdx.x * 4 + wave;      // b*N+n  in [0,20000)
    int n = node % N_;
    __shared__ float sIn[4][34];

    float e = (lane < E_) ? embed[(size_t)n * E_ + lane] : 0.f;
    float ss = e * e;
    #pragma unroll
    for (int m = 32; m >= 1; m >>= 1) ss += __shfl_xor(ss, m, 64);
    float scale = 1.f / fmaxf(sqrtf(ss), 1.f);

    if (lane < E_)            sIn[wave][lane] = e * scale;
    else if (lane < E_ + F_)  sIn[wave][lane] = feat[(size_t)node * F_ + (lane - E_)];
    __syncthreads();

    float acc = encb[lane];
    #pragma unroll
    for (int i = 0; i < E_ + F_; ++i)
        acc = fmaf(sIn[wave][i], encW[i * D_ + lane], acc);
    h[(size_t)node * D_ + lane] = acc;
}

// ---------------- neighborhood aggregate: states[t] = tanh(mean @ nbW) ------
__global__ __launch_bounds__(256) void k_agg(
    const float* __restrict__ h, const int* __restrict__ neigh,
    const float* __restrict__ nbW, const int* __restrict__ num_nodes,
    float* __restrict__ states)
{
    __shared__ float sW[D_ * D_];
    __shared__ float sM[4][D_];
    for (int i = threadIdx.x; i < D_ * D_; i += 256) sW[i] = nbW[i];

    int wave = threadIdx.x >> 6;
    int lane = threadIdx.x & 63;
    int node = blockIdx.x * 4 + wave;      // b*N+n
    int b = node / N_;
    int pad = num_nodes[b];
    __syncthreads();

    for (int t = 0; t < L_; ++t) {
        const int* nb = neigh + ((size_t)t * BN_ + node) * K_;
        float sum = 0.f; int cnt = 0;
        #pragma unroll
        for (int k = 0; k < K_; ++k) {
            int idx = nb[k];
            if (idx != pad) { sum += h[((size_t)b * N_ + idx) * D_ + lane]; cnt++; }
        }
        float m = sum / fmaxf((float)cnt, 1.f);
        sM[wave][lane] = m;
        __syncthreads();
        float acc = 0.f;
        for (int i = 0; i < D_; ++i)
            acc = fmaf(sM[wave][i], sW[i * D_ + lane], acc);
        states[((size_t)node * L_ + t) * D_ + lane] = tanhf(acc);
        __syncthreads();
    }
}

// ---------------- attention over L states + GRU update ----------------------
__global__ __launch_bounds__(256) void k_attn_gru(
    float* __restrict__ h, const float* __restrict__ states,
    const float* __restrict__ Wq, const float* __restrict__ Wk,
    const float* __restrict__ Wv, const float* __restrict__ Wo,
    const float* __restrict__ gWz, const float* __restrict__ gUz, const float* __restrict__ gbz,
    const float* __restrict__ gWr, const float* __restrict__ gUr, const float* __restrict__ gbr,
    const float* __restrict__ gWh, const float* __restrict__ gUh, const float* __restrict__ gbh)
{
    int wave = threadIdx.x >> 6;
    int lane = threadIdx.x & 63;
    int node = blockIdx.x * 4 + wave;
    __shared__ float sH[4][D_], sS[4][L_][D_], sT[4][D_], sT2[4][D_];

    float hval = h[(size_t)node * D_ + lane];
    sH[wave][lane] = hval;
    #pragma unroll
    for (int l = 0; l < L_; ++l)
        sS[wave][l][lane] = states[((size_t)node * L_ + l) * D_ + lane];
    __syncthreads();

    float q = 0.f, kk0 = 0.f, kk1 = 0.f, kk2 = 0.f, vv0 = 0.f, vv1 = 0.f, vv2 = 0.f;
    for (int i = 0; i < D_; ++i) {
        float hi = sH[wave][i];
        float s0 = sS[wave][0][i], s1 = sS[wave][1][i], s2 = sS[wave][2][i];
        q = fmaf(hi, Wq[i * D_ + lane], q);
        float wk = Wk[i * D_ + lane];
        kk0 = fmaf(s0, wk, kk0); kk1 = fmaf(s1, wk, kk1); kk2 = fmaf(s2, wk, kk2);
        float wv = Wv[i * D_ + lane];
        vv0 = fmaf(s0, wv, vv0); vv1 = fmaf(s1, wv, vv1); vv2 = fmaf(s2, wv, vv2);
    }
    // head-group (16 lanes) dot-product reduction for scores
    float p0 = q * kk0, p1 = q * kk1, p2 = q * kk2;
    #pragma unroll
    for (int m = 1; m < 16; m <<= 1) {
        p0 += __shfl_xor(p0, m, 64);
        p1 += __shfl_xor(p1, m, 64);
        p2 += __shfl_xor(p2, m, 64);
    }
    p0 *= 0.25f; p1 *= 0.25f; p2 *= 0.25f;   // / sqrt(dh=16)
    float mx = fmaxf(p0, fmaxf(p1, p2));
    float e0 = expf(p0 - mx), e1 = expf(p1 - mx), e2 = expf(p2 - mx);
    float inv = 1.f / (e0 + e1 + e2);
    float ao = (e0 * vv0 + e1 * vv1 + e2 * vv2) * inv;

    sT[wave][lane] = ao;
    __syncthreads();
    float xa = 0.f;
    for (int i = 0; i < D_; ++i) xa = fmaf(sT[wave][i], Wo[i * D_ + lane], xa);
    float x = tanhf(xa);
    sT2[wave][lane] = x;
    __syncthreads();

    float az = gbz[lane], ar = gbr[lane];
    for (int i = 0; i < D_; ++i) {
        float xi = sT2[wave][i], hi = sH[wave][i];
        az = fmaf(xi, gWz[i * D_ + lane], az); az = fmaf(hi, gUz[i * D_ + lane], az);
        ar = fmaf(xi, gWr[i * D_ + lane], ar); ar = fmaf(hi, gUr[i * D_ + lane], ar);
    }
    float z = 1.f / (1.f + expf(-az));
    float r = 1.f / (1.f + expf(-ar));
    __syncthreads();
    sT[wave][lane] = r * hval;   // (r*h) vector
    __syncthreads();
    float ah = gbh[lane];
    for (int i = 0; i < D_; ++i) {
        ah = fmaf(sT2[wave][i], gWh[i * D_ + lane], ah);
        ah = fmaf(sT[wave][i],  gUh[i * D_ + lane], ah);
    }
    float hh = tanhf(ah);
    h[(size_t)node * D_ + lane] = (1.f - z) * hval + z * hh;
}

// ---------------- edge decoder: node_weights[e] -----------------------------
// half-wave (32 lanes) per edge; lane j computes hidden unit j
__global__ __launch_bounds__(256) void k_decoder(
    const float* __restrict__ h, const int* __restrict__ adj,
    const float* __restrict__ W1, const float* __restrict__ b1,
    const float* __restrict__ W2, const float* __restrict__ b2,
    const int* __restrict__ num_nodes, float* __restrict__ nw)
{
    __shared__ float sW1[128 * 32];
    __shared__ float sW2[32];
    for (int i = threadIdx.x; i < 128 * 32; i += 256) sW1[i] = W1[i];
    if (threadIdx.x < 32) sW2[threadIdx.x] = W2[threadIdx.x];
    __syncthreads();

    int half = threadIdx.x >> 5;   // 0..7
    int j    = threadIdx.x & 31;
    float bias = b1[j], b2v = b2[0];

    for (int p = 0; p < 4; ++p) {
        int e = blockIdx.x * 32 + p * 8 + half;   // edge id < 320000
        int node = e >> 4;                        // b*N+n
        int b = node / N_;
        int a = adj[e];
        int pad = num_nodes[b];
        float am = (a == pad) ? 0.f : 1.f;
        const float* hown = h + (size_t)node * D_;
        const float* hnbr = h + ((size_t)b * N_ + (a == pad ? 0 : a)) * D_;
        float acc = bias;
        for (int i = 0; i < D_; ++i) acc = fmaf(am * hown[i], sW1[i * 32 + j], acc);
        for (int i = 0; i < D_; ++i) acc = fmaf(am * hnbr[i], sW1[(D_ + i) * 32 + j], acc);
        float t = tanhf(acc);
        float part = t * sW2[j];
        #pragma unroll
        for (int m = 1; m < 32; m <<= 1) part += __shfl_xor(part, m, 64);
        if (j == 0) nw[e] = part + b2v;
    }
}

// ---------------- dual vars (per node scalar) + dual_demand -----------------
__global__ __launch_bounds__(256) void k_dualvars(
    const float* __restrict__ h, const float* __restrict__ W1,
    const float* __restrict__ b1, const float* __restrict__ W2,
    const float* __restrict__ b2, const float* __restrict__ demands,
    float* __restrict__ dv, float* __restrict__ acc_out)
{
    __shared__ float sW1[D_ * 32];
    __shared__ float sW2[32];
    for (int i = threadIdx.x; i < D_ * 32; i += 256) sW1[i] = W1[i];
    if (threadIdx.x < 32) sW2[threadIdx.x] = W2[threadIdx.x];
    __syncthreads();

    int half = threadIdx.x >> 5;
    int j    = threadIdx.x & 31;
    int node = blockIdx.x * 8 + half;             // < 20000
    const float* hp = h + (size_t)node * D_;
    float acc = b1[j];
    for (int i = 0; i < D_; ++i) acc = fmaf(hp[i], sW1[i * 32 + j], acc);
    float t = tanhf(acc);
    float part = t * sW2[j];
    #pragma unroll
    for (int m = 1; m < 32; m <<= 1) part += __shfl_xor(part, m, 64);
    if (j == 0) {
        float v = part + b2[0];
        dv[node] = v;
        int b = node / N_;
        atomicAdd(&acc_out[b * 3 + 2], v * demands[node]);
    }
}

// ---------------- dest softmax over permuted groups -------------------------
__global__ void k_dest(
    const float* __restrict__ nw, const int* __restrict__ in_idx,
    const int* __restrict__ inv_adj, const int* __restrict__ num_nodes,
    float* __restrict__ dest)
{
    int t = blockIdx.x * 256 + threadIdx.x;
    if (t >= BN_) return;
    int b = t / N_;
    int pad = num_nodes[b];
    float vals[K_]; float mx = -INFINITY;
    #pragma unroll
    for (int k = 0; k < K_; ++k) {
        int jj = in_idx[(size_t)t * K_ + k];
        float g = nw[(size_t)b * NK_ + jj];
        float im = (inv_adj[(size_t)t * K_ + k] == pad) ? 1.f : 0.f;
        float v = g - BIG_ * im;
        vals[k] = v; mx = fmaxf(mx, v);
    }
    float s = 0.f;
    #pragma unroll
    for (int k = 0; k < K_; ++k) { vals[k] = expf(vals[k] - mx); s += vals[k]; }
    float invs = 1.f / s;
    #pragma unroll
    for (int k = 0; k < K_; ++k) dest[(size_t)t * K_ + k] = vals[k] * invs;
}

// ---------------- normalized_weights + flow0 --------------------------------
__global__ void k_normw(
    const float* __restrict__ nw, const float* __restrict__ dest,
    const int* __restrict__ rev, const int* __restrict__ adj,
    const int* __restrict__ num_nodes, const float* __restrict__ demands,
    float* __restrict__ normw, float* __restrict__ flow0)
{
    int t = blockIdx.x * 256 + threadIdx.x;
    if (t >= BN_) return;
    int b = t / N_;
    int pad = num_nodes[b];
    float vals[K_]; float mx = -INFINITY;
    #pragma unroll
    for (int k = 0; k < K_; ++k) {
        size_t e = (size_t)t * K_ + k;
        float v = nw[e] * dest[(size_t)b * NK_ + rev[e]];
        float m = (adj[e] == pad) ? 1.f : 0.f;
        v -= BIG_ * m;
        vals[k] = v; mx = fmaxf(mx, v);
    }
    float s = 0.f;
    #pragma unroll
    for (int k = 0; k < K_; ++k) { vals[k] = expf(vals[k] - mx); s += vals[k]; }
    float invs = 1.f / s;
    float supply = fmaxf(-demands[t], 0.f);
    #pragma unroll
    for (int k = 0; k < K_; ++k) {
        float w = vals[k] * invs;
        normw[(size_t)t * K_ + k] = w;
        flow0[(size_t)t * K_ + k] = w * supply;
    }
}

// ---------------- one MCF flow step -----------------------------------------
__global__ void k_flow(
    const float* __restrict__ cur, const float* __restrict__ normw,
    const int* __restrict__ in_idx, const int* __restrict__ inv_adj,
    const int* __restrict__ num_nodes, const float* __restrict__ demands,
    float* __restrict__ nxt)
{
    int t = blockIdx.x * 256 + threadIdx.x;
    if (t >= BN_) return;
    int b = t / N_;
    int pad = num_nodes[b];
    float inflow = 0.f;
    #pragma unroll
    for (int k = 0; k < K_; ++k) {
        size_t e = (size_t)t * K_ + k;
        if (inv_adj[e] != pad) inflow += cur[(size_t)b * NK_ + in_idx[e]];
    }
    float tot = inflow + fmaxf(-demands[t], 0.f);
    #pragma unroll
    for (int k = 0; k < K_; ++k)
        nxt[(size_t)t * K_ + k] = normw[(size_t)t * K_ + k] * tot;
}

// ---------------- dual_diff -------------------------------------------------
__global__ void k_dualdiff(
    const float* __restrict__ dv, const int* __restrict__ adj,
    const int* __restrict__ num_nodes, float* __restrict__ dd)
{
    int e = blockIdx.x * 256 + threadIdx.x;   // < 320000 exact
    int node = e >> 4;
    int b = node / N_;
    int pad = num_nodes[b];
    int a = adj[e];
    float am = (a == pad) ? 0.f : 1.f;
    float dtr = (a == pad) ? 0.f : dv[(size_t)b * N_ + a];
    dd[e] = dtr - am * dv[node];
}

// ---------------- dual iterations + both cost reductions --------------------
__global__ __launch_bounds__(256) void k_dualred(
    const float* __restrict__ el, const float* __restrict__ dd,
    const int* __restrict__ adj, const int* __restrict__ num_nodes,
    const float* __restrict__ flow, float* __restrict__ acc_out)
{
    int b = blockIdx.y;
    int ein = blockIdx.x * 256 + threadIdx.x;
    float c0 = 0.f, c1 = 0.f;
    if (ein < NK_) {
        size_t e = (size_t)b * NK_ + ein;
        int pad = num_nodes[b];
        float l = el[e], d = dd[e];
        float am = (adj[e] == pad) ? 0.f : 1.f;
        float f = 0.f, ac = 0.f;
        #pragma unroll
        for (int it = 0; it < 10; ++it) {
            float g = 2.f * l * f + d;
            ac = 0.9f * ac + 0.01f * g;
            f = fmaxf(f - ac, 0.f) * am;
        }
        float fl = flow[e];
        c0 = l * fl * fl;          // flow_cost term
        c1 = l * f * f + d * f;    // dual flow term
    }
    #pragma unroll
    for (int m = 1; m < 64; m <<= 1) { c0 += __shfl_xor(c0, m, 64); c1 += __shfl_xor(c1, m, 64); }
    __shared__ float s0[4], s1[4];
    int wave = threadIdx.x >> 6, lane = threadIdx.x & 63;
    if (lane == 0) { s0[wave] = c0; s1[wave] = c1; }
    __syncthreads();
    if (threadIdx.x == 0) {
        atomicAdd(&acc_out[b * 3 + 0], s0[0] + s0[1] + s0[2] + s0[3]);
        atomicAdd(&acc_out[b * 3 + 1], s1[0] + s1[1] + s1[2] + s1[3]);
    }
}

// ---------------- finalize --------------------------------------------------
__global__ void k_final(const float* __restrict__ acc, float* __restrict__ out) {
    int b = threadIdx.x;
    if (b < B_) out[b] = acc[b * 3 + 0] - acc[b * 3 + 1] + acc[b * 3 + 2];
}

extern "C" void kernel_launch(void* const* d_in, const int* in_sizes, int n_in,
                              void* d_out, int out_size, void* d_ws, size_t ws_size,
                              hipStream_t stream)
{
    const float* demands = (const float*)d_in[0];
    const float* feat    = (const float*)d_in[1];
    const float* el      = (const float*)d_in[2];
    const float* embed   = (const float*)d_in[3];
    const float* encW    = (const float*)d_in[4];
    const float* encb    = (const float*)d_in[5];
    const float* nbW     = (const float*)d_in[6];
    const float* Wq      = (const float*)d_in[7];
    const float* Wk      = (const float*)d_in[8];
    const float* Wv      = (const float*)d_in[9];
    const float* Wo      = (const float*)d_in[10];
    const float* gWz     = (const float*)d_in[11];
    const float* gUz     = (const float*)d_in[12];
    const float* gbz     = (const float*)d_in[13];
    const float* gWr     = (const float*)d_in[14];
    const float* gUr     = (const float*)d_in[15];
    const float* gbr     = (const float*)d_in[16];
    const float* gWh     = (const float*)d_in[17];
    const float* gUh     = (const float*)d_in[18];
    const float* gbh     = (const float*)d_in[19];
    const float* decW1   = (const float*)d_in[20];
    const float* decb1   = (const float*)d_in[21];
    const float* decW2   = (const float*)d_in[22];
    const float* decb2   = (const float*)d_in[23];
    const float* dualW1  = (const float*)d_in[24];
    const float* dualb1  = (const float*)d_in[25];
    const float* dualW2  = (const float*)d_in[26];
    const float* dualb2  = (const float*)d_in[27];
    const int* adj       = (const int*)d_in[28];
    const int* invadj    = (const int*)d_in[29];
    const int* neigh     = (const int*)d_in[30];
    const int* inidx     = (const int*)d_in[31];
    const int* revidx    = (const int*)d_in[32];
    const int* numn      = (const int*)d_in[33];

    float* ws     = (float*)d_ws;
    float* h      = ws;                       // 1,280,000 f
    float* states = ws + 1280000;             // 3,840,000 f
    // region reuse after graph layers:
    float* nw     = states;                   // 320,000
    float* dest   = states + 320000;          // 320,000
    float* normw  = states + 640000;          // 320,000
    float* flowA  = states + 960000;          // 320,000
    float* flowB  = states + 1280000;         // 320,000
    float* dd     = states + 1600000;         // 320,000
    float* dv     = states + 1920000;         // 20,000
    float* acc    = ws + 5120000;             // 16

    k_zero<<<1, 64, 0, stream>>>(acc);
    k_encode<<<BN_ / 4, 256, 0, stream>>>(embed, feat, encW, encb, h);

    for (int layer = 0; layer < 2; ++layer) {
        k_agg<<<BN_ / 4, 256, 0, stream>>>(h, neigh, nbW, numn, states);
        k_attn_gru<<<BN_ / 4, 256, 0, stream>>>(h, states, Wq, Wk, Wv, Wo,
                                                gWz, gUz, gbz, gWr, gUr, gbr,
                                                gWh, gUh, gbh);
    }

    k_decoder<<<(B_ * NK_) / 32, 256, 0, stream>>>(h, adj, decW1, decb1, decW2, decb2, numn, nw);
    k_dualvars<<<BN_ / 8, 256, 0, stream>>>(h, dualW1, dualb1, dualW2, dualb2, demands, dv, acc);
    k_dest<<<(BN_ + 255) / 256, 256, 0, stream>>>(nw, inidx, invadj, numn, dest);
    k_normw<<<(BN_ + 255) / 256, 256, 0, stream>>>(nw, dest, revidx, adj, numn, demands, normw, flowA);

    float* cur = flowA; float* nxt = flowB;
    for (int it = 0; it < 10; ++it) {
        k_flow<<<(BN_ + 255) / 256, 256, 0, stream>>>(cur, normw, inidx, invadj, numn, demands, nxt);
        float* tmp = cur; cur = nxt; nxt = tmp;
    }

    k_dualdiff<<<(B_ * NK_) / 256, 256, 0, stream>>>(dv, adj, numn, dd);
    dim3 gred((NK_ + 255) / 256, B_);
    k_dualred<<<gred, 256, 0, stream>>>(el, dd, adj, numn, cur, acc);
    k_final<<<1, 64, 0, stream>>>(acc, (float*)d_out);
}

// Round 2
// 969.062 us; speedup vs baseline: 1.0341x; 1.0341x over previous
//
#include <hip/hip_runtime.h>
#include <math.h>

#define B_ 4
#define N_ 5000
#define K_ 16
#define L_ 3
#define F_ 2
#define E_ 32
#define D_ 64
#define H_ 4
#define BN_ (B_*N_)          /* 20000 */
#define NK_ (N_*K_)          /* 80000 */
#define BIG_ 1.0e9f

// acc layout: accumulator c of batch b lives at acc[(b*3+c)*16]  (64B apart,
// no shared cache lines between any two accumulators -> no atomic line ping-pong)

// ---------------- zero the accumulators -------------------------------------
__global__ void k_zero(float* __restrict__ acc) {
    if (threadIdx.x < 192) acc[threadIdx.x] = 0.f;
}

// ---------------- encoder: h = [emb_norm, feat] @ enc_W + enc_b -------------
// one wave per node, lane d computes h[d]; shuffle-broadcast, no LDS
__global__ __launch_bounds__(256) void k_encode(
    const float* __restrict__ embed, const float* __restrict__ feat,
    const float* __restrict__ encW, const float* __restrict__ encb,
    float* __restrict__ h)
{
    int wave = threadIdx.x >> 6;
    int lane = threadIdx.x & 63;
    int node = blockIdx.x * 4 + wave;      // b*N+n  in [0,20000)
    int n = node % N_;

    float e = (lane < E_) ? embed[(size_t)n * E_ + lane] : 0.f;
    float ss = e * e;
    #pragma unroll
    for (int m = 32; m >= 1; m >>= 1) ss += __shfl_xor(ss, m, 64);
    float scale = 1.f / fmaxf(sqrtf(ss), 1.f);

    float inval = (lane < E_) ? e * scale
                : (lane < E_ + F_) ? feat[(size_t)node * F_ + (lane - E_)]
                : 0.f;

    float acc = encb[lane];
    #pragma unroll
    for (int i = 0; i < E_ + F_; ++i)
        acc = fmaf(__shfl(inval, i, 64), encW[i * D_ + lane], acc);
    h[(size_t)node * D_ + lane] = acc;
}

// ---------------- neighborhood aggregate: states[t] = tanh(mean @ nbW) ------
// 16 nodes per block (4 per wave), shuffle-broadcast matmul, no barriers in loop
__global__ __launch_bounds__(256) void k_agg(
    const float* __restrict__ h, const int* __restrict__ neigh,
    const float* __restrict__ nbW, const int* __restrict__ num_nodes,
    float* __restrict__ states)
{
    __shared__ float sW[D_ * D_];
    for (int i = threadIdx.x; i < D_ * D_; i += 256) sW[i] = nbW[i];
    __syncthreads();

    int wave = threadIdx.x >> 6;
    int lane = threadIdx.x & 63;

    #pragma unroll 1
    for (int p = 0; p < 4; ++p) {
        int node = blockIdx.x * 16 + p * 4 + wave;   // b*N+n
        int b = node / N_;
        int pad = num_nodes[b];
        const float* hb = h + (size_t)b * N_ * D_;

        for (int t = 0; t < L_; ++t) {
            const int* nb = neigh + ((size_t)t * BN_ + node) * K_;
            float sum = 0.f; int cnt = 0;
            #pragma unroll
            for (int k = 0; k < K_; ++k) {
                int idx = nb[k];
                if (idx != pad) { sum += hb[(size_t)idx * D_ + lane]; cnt++; }
            }
            float m = sum / fmaxf((float)cnt, 1.f);
            float acc = 0.f;
            #pragma unroll 8
            for (int i = 0; i < D_; ++i)
                acc = fmaf(__shfl(m, i, 64), sW[i * D_ + lane], acc);
            states[((size_t)node * L_ + t) * D_ + lane] = tanhf(acc);
        }
    }
}

// ---------------- attention over L states + GRU update ----------------------
// one wave per node, fully register/shuffle-based, no LDS, no barriers
__global__ __launch_bounds__(256) void k_attn_gru(
    float* __restrict__ h, const float* __restrict__ states,
    const float* __restrict__ Wq, const float* __restrict__ Wk,
    const float* __restrict__ Wv, const float* __restrict__ Wo,
    const float* __restrict__ gWz, const float* __restrict__ gUz, const float* __restrict__ gbz,
    const float* __restrict__ gWr, const float* __restrict__ gUr, const float* __restrict__ gbr,
    const float* __restrict__ gWh, const float* __restrict__ gUh, const float* __restrict__ gbh)
{
    int wave = threadIdx.x >> 6;
    int lane = threadIdx.x & 63;
    int node = blockIdx.x * 4 + wave;

    float hval = h[(size_t)node * D_ + lane];
    float st0 = states[((size_t)node * L_ + 0) * D_ + lane];
    float st1 = states[((size_t)node * L_ + 1) * D_ + lane];
    float st2 = states[((size_t)node * L_ + 2) * D_ + lane];

    float q = 0.f, kk0 = 0.f, kk1 = 0.f, kk2 = 0.f, vv0 = 0.f, vv1 = 0.f, vv2 = 0.f;
    #pragma unroll 8
    for (int i = 0; i < D_; ++i) {
        float hi = __shfl(hval, i, 64);
        float s0 = __shfl(st0, i, 64), s1 = __shfl(st1, i, 64), s2 = __shfl(st2, i, 64);
        q = fmaf(hi, Wq[i * D_ + lane], q);
        float wk = Wk[i * D_ + lane];
        kk0 = fmaf(s0, wk, kk0); kk1 = fmaf(s1, wk, kk1); kk2 = fmaf(s2, wk, kk2);
        float wv = Wv[i * D_ + lane];
        vv0 = fmaf(s0, wv, vv0); vv1 = fmaf(s1, wv, vv1); vv2 = fmaf(s2, wv, vv2);
    }
    // head-group (16 lanes) dot-product reduction for scores
    float p0 = q * kk0, p1 = q * kk1, p2 = q * kk2;
    #pragma unroll
    for (int m = 1; m < 16; m <<= 1) {
        p0 += __shfl_xor(p0, m, 64);
        p1 += __shfl_xor(p1, m, 64);
        p2 += __shfl_xor(p2, m, 64);
    }
    p0 *= 0.25f; p1 *= 0.25f; p2 *= 0.25f;   // / sqrt(dh=16)
    float mx = fmaxf(p0, fmaxf(p1, p2));
    float e0 = expf(p0 - mx), e1 = expf(p1 - mx), e2 = expf(p2 - mx);
    float inv = 1.f / (e0 + e1 + e2);
    float ao = (e0 * vv0 + e1 * vv1 + e2 * vv2) * inv;

    float xa = 0.f;
    #pragma unroll 8
    for (int i = 0; i < D_; ++i)
        xa = fmaf(__shfl(ao, i, 64), Wo[i * D_ + lane], xa);
    float x = tanhf(xa);

    float az = gbz[lane], ar = gbr[lane];
    #pragma unroll 8
    for (int i = 0; i < D_; ++i) {
        float xi = __shfl(x, i, 64), hi = __shfl(hval, i, 64);
        az = fmaf(xi, gWz[i * D_ + lane], az); az = fmaf(hi, gUz[i * D_ + lane], az);
        ar = fmaf(xi, gWr[i * D_ + lane], ar); ar = fmaf(hi, gUr[i * D_ + lane], ar);
    }
    float z = 1.f / (1.f + expf(-az));
    float r = 1.f / (1.f + expf(-ar));
    float rh = r * hval;

    float ah = gbh[lane];
    #pragma unroll 8
    for (int i = 0; i < D_; ++i) {
        ah = fmaf(__shfl(x, i, 64),  gWh[i * D_ + lane], ah);
        ah = fmaf(__shfl(rh, i, 64), gUh[i * D_ + lane], ah);
    }
    float hh = tanhf(ah);
    h[(size_t)node * D_ + lane] = (1.f - z) * hval + z * hh;
}

// ---------------- edge decoder: node_weights[e] -----------------------------
// half-wave (32 lanes) per edge, 128 edges per block; coalesced h loads +
// width-32 shuffle broadcast
__global__ __launch_bounds__(256) void k_decoder(
    const float* __restrict__ h, const int* __restrict__ adj,
    const float* __restrict__ W1, const float* __restrict__ b1,
    const float* __restrict__ W2, const float* __restrict__ b2,
    const int* __restrict__ num_nodes, float* __restrict__ nw)
{
    __shared__ float sW1[128 * 32];
    __shared__ float sW2[32];
    for (int i = threadIdx.x; i < 128 * 32; i += 256) sW1[i] = W1[i];
    if (threadIdx.x < 32) sW2[threadIdx.x] = W2[threadIdx.x];
    __syncthreads();

    int half = threadIdx.x >> 5;   // 0..7
    int j    = threadIdx.x & 31;
    float bias = b1[j], b2v = b2[0];

    #pragma unroll 1
    for (int p = 0; p < 16; ++p) {
        int e = blockIdx.x * 128 + p * 8 + half;  // edge id < 320000
        int node = e >> 4;                        // b*N+n
        int b = node / N_;
        int a = adj[e];
        int pad = num_nodes[b];
        float am = (a == pad) ? 0.f : 1.f;
        const float* hown = h + (size_t)node * D_;
        const float* hnbr = h + ((size_t)b * N_ + (a == pad ? 0 : a)) * D_;
        float ho0 = am * hown[j], ho1 = am * hown[j + 32];
        float hn0 = am * hnbr[j], hn1 = am * hnbr[j + 32];
        float acc = bias;
        #pragma unroll 8
        for (int i = 0; i < 32; ++i) {
            acc = fmaf(__shfl(ho0, i, 32), sW1[i * 32 + j],        acc);
            acc = fmaf(__shfl(ho1, i, 32), sW1[(i + 32) * 32 + j], acc);
            acc = fmaf(__shfl(hn0, i, 32), sW1[(i + 64) * 32 + j], acc);
            acc = fmaf(__shfl(hn1, i, 32), sW1[(i + 96) * 32 + j], acc);
        }
        float t = tanhf(acc);
        float part = t * sW2[j];
        #pragma unroll
        for (int m = 1; m < 32; m <<= 1) part += __shfl_xor(part, m, 64);
        if (j == 0) nw[e] = part + b2v;
    }
}

// ---------------- dual vars (per node scalar) + dual_demand -----------------
// 40 nodes per block (40 | 5000 -> batch-uniform); ONE atomic per block
__global__ __launch_bounds__(256) void k_dualvars(
    const float* __restrict__ h, const float* __restrict__ W1,
    const float* __restrict__ b1, const float* __restrict__ W2,
    const float* __restrict__ b2, const float* __restrict__ demands,
    const int* __restrict__ num_nodes,
    float* __restrict__ dv, float* __restrict__ acc_out)
{
    __shared__ float sW1[D_ * 32];
    __shared__ float sW2[32];
    __shared__ float sPart[8];
    for (int i = threadIdx.x; i < D_ * 32; i += 256) sW1[i] = W1[i];
    if (threadIdx.x < 32) sW2[threadIdx.x] = W2[threadIdx.x];
    __syncthreads();

    int half = threadIdx.x >> 5;
    int j    = threadIdx.x & 31;
    int b = (blockIdx.x * 40) / N_;
    float bias = b1[j], b2v = b2[0];
    float local = 0.f;

    #pragma unroll 1
    for (int p = 0; p < 5; ++p) {
        int node = blockIdx.x * 40 + p * 8 + half;    // < 20000
        const float* hp = h + (size_t)node * D_;
        float h0 = hp[j], h1 = hp[j + 32];
        float acc = bias;
        #pragma unroll 8
        for (int i = 0; i < 32; ++i) {
            acc = fmaf(__shfl(h0, i, 32), sW1[i * 32 + j],        acc);
            acc = fmaf(__shfl(h1, i, 32), sW1[(i + 32) * 32 + j], acc);
        }
        float t = tanhf(acc);
        float part = t * sW2[j];
        #pragma unroll
        for (int m = 1; m < 32; m <<= 1) part += __shfl_xor(part, m, 64);
        if (j == 0) {
            float v = part + b2v;
            dv[node] = v;
            local += v * demands[node];
        }
    }
    if (j == 0) sPart[half] = local;
    __syncthreads();
    if (threadIdx.x == 0) {
        float s = 0.f;
        #pragma unroll
        for (int i = 0; i < 8; ++i) s += sPart[i];
        atomicAdd(&acc_out[(b * 3 + 2) * 16], s);
    }
}

// ---------------- dest softmax over permuted groups -------------------------
__global__ void k_dest(
    const float* __restrict__ nw, const int* __restrict__ in_idx,
    const int* __restrict__ inv_adj, const int* __restrict__ num_nodes,
    float* __restrict__ dest)
{
    int t = blockIdx.x * 256 + threadIdx.x;
    if (t >= BN_) return;
    int b = t / N_;
    int pad = num_nodes[b];
    float vals[K_]; float mx = -INFINITY;
    #pragma unroll
    for (int k = 0; k < K_; ++k) {
        int jj = in_idx[(size_t)t * K_ + k];
        float g = nw[(size_t)b * NK_ + jj];
        float im = (inv_adj[(size_t)t * K_ + k] == pad) ? 1.f : 0.f;
        float v = g - BIG_ * im;
        vals[k] = v; mx = fmaxf(mx, v);
    }
    float s = 0.f;
    #pragma unroll
    for (int k = 0; k < K_; ++k) { vals[k] = expf(vals[k] - mx); s += vals[k]; }
    float invs = 1.f / s;
    #pragma unroll
    for (int k = 0; k < K_; ++k) dest[(size_t)t * K_ + k] = vals[k] * invs;
}

// ---------------- normalized_weights + flow0 --------------------------------
__global__ void k_normw(
    const float* __restrict__ nw, const float* __restrict__ dest,
    const int* __restrict__ rev, const int* __restrict__ adj,
    const int* __restrict__ num_nodes, const float* __restrict__ demands,
    float* __restrict__ normw, float* __restrict__ flow0)
{
    int t = blockIdx.x * 256 + threadIdx.x;
    if (t >= BN_) return;
    int b = t / N_;
    int pad = num_nodes[b];
    float vals[K_]; float mx = -INFINITY;
    #pragma unroll
    for (int k = 0; k < K_; ++k) {
        size_t e = (size_t)t * K_ + k;
        float v = nw[e] * dest[(size_t)b * NK_ + rev[e]];
        float m = (adj[e] == pad) ? 1.f : 0.f;
        v -= BIG_ * m;
        vals[k] = v; mx = fmaxf(mx, v);
    }
    float s = 0.f;
    #pragma unroll
    for (int k = 0; k < K_; ++k) { vals[k] = expf(vals[k] - mx); s += vals[k]; }
    float invs = 1.f / s;
    float supply = fmaxf(-demands[t], 0.f);
    #pragma unroll
    for (int k = 0; k < K_; ++k) {
        float w = vals[k] * invs;
        normw[(size_t)t * K_ + k] = w;
        flow0[(size_t)t * K_ + k] = w * supply;
    }
}

// ---------------- one MCF flow step -----------------------------------------
__global__ void k_flow(
    const float* __restrict__ cur, const float* __restrict__ normw,
    const int* __restrict__ in_idx, const int* __restrict__ inv_adj,
    const int* __restrict__ num_nodes, const float* __restrict__ demands,
    float* __restrict__ nxt)
{
    int t = blockIdx.x * 256 + threadIdx.x;
    if (t >= BN_) return;
    int b = t / N_;
    int pad = num_nodes[b];
    float inflow = 0.f;
    #pragma unroll
    for (int k = 0; k < K_; ++k) {
        size_t e = (size_t)t * K_ + k;
        if (inv_adj[e] != pad) inflow += cur[(size_t)b * NK_ + in_idx[e]];
    }
    float tot = inflow + fmaxf(-demands[t], 0.f);
    #pragma unroll
    for (int k = 0; k < K_; ++k)
        nxt[(size_t)t * K_ + k] = normw[(size_t)t * K_ + k] * tot;
}

// ---------------- dual_diff -------------------------------------------------
__global__ void k_dualdiff(
    const float* __restrict__ dv, const int* __restrict__ adj,
    const int* __restrict__ num_nodes, float* __restrict__ dd)
{
    int e = blockIdx.x * 256 + threadIdx.x;   // < 320000 exact
    int node = e >> 4;
    int b = node / N_;
    int pad = num_nodes[b];
    int a = adj[e];
    float am = (a == pad) ? 0.f : 1.f;
    float dtr = (a == pad) ? 0.f : dv[(size_t)b * N_ + a];
    dd[e] = dtr - am * dv[node];
}

// ---------------- dual iterations + both cost reductions --------------------
__global__ __launch_bounds__(256) void k_dualred(
    const float* __restrict__ el, const float* __restrict__ dd,
    const int* __restrict__ adj, const int* __restrict__ num_nodes,
    const float* __restrict__ flow, float* __restrict__ acc_out)
{
    int b = blockIdx.y;
    int ein = blockIdx.x * 256 + threadIdx.x;
    float c0 = 0.f, c1 = 0.f;
    if (ein < NK_) {
        size_t e = (size_t)b * NK_ + ein;
        int pad = num_nodes[b];
        float l = el[e], d = dd[e];
        float am = (adj[e] == pad) ? 0.f : 1.f;
        float f = 0.f, ac = 0.f;
        #pragma unroll
        for (int it = 0; it < 10; ++it) {
            float g = 2.f * l * f + d;
            ac = 0.9f * ac + 0.01f * g;
            f = fmaxf(f - ac, 0.f) * am;
        }
        float fl = flow[e];
        c0 = l * fl * fl;          // flow_cost term
        c1 = l * f * f + d * f;    // dual flow term
    }
    #pragma unroll
    for (int m = 1; m < 64; m <<= 1) { c0 += __shfl_xor(c0, m, 64); c1 += __shfl_xor(c1, m, 64); }
    __shared__ float s0[4], s1[4];
    int wave = threadIdx.x >> 6, lane = threadIdx.x & 63;
    if (lane == 0) { s0[wave] = c0; s1[wave] = c1; }
    __syncthreads();
    if (threadIdx.x == 0) {
        atomicAdd(&acc_out[(b * 3 + 0) * 16], s0[0] + s0[1] + s0[2] + s0[3]);
        atomicAdd(&acc_out[(b * 3 + 1) * 16], s1[0] + s1[1] + s1[2] + s1[3]);
    }
}

// ---------------- finalize --------------------------------------------------
__global__ void k_final(const float* __restrict__ acc, float* __restrict__ out) {
    int b = threadIdx.x;
    if (b < B_)
        out[b] = acc[(b * 3 + 0) * 16] - acc[(b * 3 + 1) * 16] + acc[(b * 3 + 2) * 16];
}

extern "C" void kernel_launch(void* const* d_in, const int* in_sizes, int n_in,
                              void* d_out, int out_size, void* d_ws, size_t ws_size,
                              hipStream_t stream)
{
    const float* demands = (const float*)d_in[0];
    const float* feat    = (const float*)d_in[1];
    const float* el      = (const float*)d_in[2];
    const float* embed   = (const float*)d_in[3];
    const float* encW    = (const float*)d_in[4];
    const float* encb    = (const float*)d_in[5];
    const float* nbW     = (const float*)d_in[6];
    const float* Wq      = (const float*)d_in[7];
    const float* Wk      = (const float*)d_in[8];
    const float* Wv      = (const float*)d_in[9];
    const float* Wo      = (const float*)d_in[10];
    const float* gWz     = (const float*)d_in[11];
    const float* gUz     = (const float*)d_in[12];
    const float* gbz     = (const float*)d_in[13];
    const float* gWr     = (const float*)d_in[14];
    const float* gUr     = (const float*)d_in[15];
    const float* gbr     = (const float*)d_in[16];
    const float* gWh     = (const float*)d_in[17];
    const float* gUh     = (const float*)d_in[18];
    const float* gbh     = (const float*)d_in[19];
    const float* decW1   = (const float*)d_in[20];
    const float* decb1   = (const float*)d_in[21];
    const float* decW2   = (const float*)d_in[22];
    const float* decb2   = (const float*)d_in[23];
    const float* dualW1  = (const float*)d_in[24];
    const float* dualb1  = (const float*)d_in[25];
    const float* dualW2  = (const float*)d_in[26];
    const float* dualb2  = (const float*)d_in[27];
    const int* adj       = (const int*)d_in[28];
    const int* invadj    = (const int*)d_in[29];
    const int* neigh     = (const int*)d_in[30];
    const int* inidx     = (const int*)d_in[31];
    const int* revidx    = (const int*)d_in[32];
    const int* numn      = (const int*)d_in[33];

    float* ws     = (float*)d_ws;
    float* h      = ws;                       // 1,280,000 f
    float* states = ws + 1280000;             // 3,840,000 f
    // region reuse after graph layers:
    float* nw     = states;                   // 320,000
    float* dest   = states + 320000;          // 320,000
    float* normw  = states + 640000;          // 320,000
    float* flowA  = states + 960000;          // 320,000
    float* flowB  = states + 1280000;         // 320,000
    float* dd     = states + 1600000;         // 320,000
    float* dv     = states + 1920000;         // 20,000
    float* acc    = ws + 5120000;             // 192 f (12 accumulators, 64B apart)

    k_zero<<<1, 256, 0, stream>>>(acc);
    k_encode<<<BN_ / 4, 256, 0, stream>>>(embed, feat, encW, encb, h);

    for (int layer = 0; layer < 2; ++layer) {
        k_agg<<<BN_ / 16, 256, 0, stream>>>(h, neigh, nbW, numn, states);
        k_attn_gru<<<BN_ / 4, 256, 0, stream>>>(h, states, Wq, Wk, Wv, Wo,
                                                gWz, gUz, gbz, gWr, gUr, gbr,
                                                gWh, gUh, gbh);
    }

    k_decoder<<<(B_ * NK_) / 128, 256, 0, stream>>>(h, adj, decW1, decb1, decW2, decb2, numn, nw);
    k_dualvars<<<BN_ / 40, 256, 0, stream>>>(h, dualW1, dualb1, dualW2, dualb2, demands, numn, dv, acc);
    k_dest<<<(BN_ + 255) / 256, 256, 0, stream>>>(nw, inidx, invadj, numn, dest);
    k_normw<<<(BN_ + 255) / 256, 256, 0, stream>>>(nw, dest, revidx, adj, numn, demands, normw, flowA);

    float* cur = flowA; float* nxt = flowB;
    for (int it = 0; it < 10; ++it) {
        k_flow<<<(BN_ + 255) / 256, 256, 0, stream>>>(cur, normw, inidx, invadj, numn, demands, nxt);
        float* tmp = cur; cur = nxt; nxt = tmp;
    }

    k_dualdiff<<<(B_ * NK_) / 256, 256, 0, stream>>>(dv, adj, numn, dd);
    dim3 gred((NK_ + 255) / 256, B_);
    k_dualred<<<gred, 256, 0, stream>>>(el, dd, adj, numn, cur, acc);
    k_final<<<1, 64, 0, stream>>>(acc, (float*)d_out);
}

// Round 3
// 717.623 us; speedup vs baseline: 1.3964x; 1.3504x over previous
//
#include <hip/hip_runtime.h>
#include <math.h>

#define B_ 4
#define N_ 5000
#define K_ 16
#define L_ 3
#define F_ 2
#define E_ 32
#define D_ 64
#define H_ 4
#define BN_ (B_*N_)          /* 20000 */
#define NK_ (N_*K_)          /* 80000 */
#define BIG_ 1.0e9f

// acc layout: accumulator c of batch b lives at acc[(b*3+c)*16]  (64B apart)

// ---------------- zero the accumulators -------------------------------------
__global__ void k_zero(float* __restrict__ acc) {
    if (threadIdx.x < 192) acc[threadIdx.x] = 0.f;
}

// ---------------- encoder: h = [emb_norm, feat] @ enc_W + enc_b -------------
__global__ __launch_bounds__(256) void k_encode(
    const float* __restrict__ embed, const float* __restrict__ feat,
    const float* __restrict__ encW, const float* __restrict__ encb,
    float* __restrict__ h)
{
    int wave = threadIdx.x >> 6;
    int lane = threadIdx.x & 63;
    int node = blockIdx.x * 4 + wave;      // b*N+n  in [0,20000)
    int n = node % N_;

    float e = (lane < E_) ? embed[(size_t)n * E_ + lane] : 0.f;
    float ss = e * e;
    #pragma unroll
    for (int m = 32; m >= 1; m >>= 1) ss += __shfl_xor(ss, m, 64);
    float scale = 1.f / fmaxf(sqrtf(ss), 1.f);

    float inval = (lane < E_) ? e * scale
                : (lane < E_ + F_) ? feat[(size_t)node * F_ + (lane - E_)]
                : 0.f;

    float acc = encb[lane];
    #pragma unroll
    for (int i = 0; i < E_ + F_; ++i)
        acc = fmaf(__shfl(inval, i, 64), encW[i * D_ + lane], acc);
    h[(size_t)node * D_ + lane] = acc;
}

// ---------------- neighborhood aggregate: states[t] = tanh(mean @ nbW) ------
__global__ __launch_bounds__(256) void k_agg(
    const float* __restrict__ h, const int* __restrict__ neigh,
    const float* __restrict__ nbW, const int* __restrict__ num_nodes,
    float* __restrict__ states)
{
    __shared__ float sW[D_ * D_];
    for (int i = threadIdx.x; i < D_ * D_; i += 256) sW[i] = nbW[i];
    __syncthreads();

    int wave = threadIdx.x >> 6;
    int lane = threadIdx.x & 63;

    #pragma unroll 1
    for (int p = 0; p < 4; ++p) {
        int node = blockIdx.x * 16 + p * 4 + wave;   // b*N+n
        int b = node / N_;
        int pad = num_nodes[b];
        const float* hb = h + (size_t)b * N_ * D_;

        for (int t = 0; t < L_; ++t) {
            const int* nb = neigh + ((size_t)t * BN_ + node) * K_;
            float sum = 0.f; int cnt = 0;
            #pragma unroll
            for (int k = 0; k < K_; ++k) {
                int idx = nb[k];
                if (idx != pad) { sum += hb[(size_t)idx * D_ + lane]; cnt++; }
            }
            float m = sum / fmaxf((float)cnt, 1.f);
            float acc = 0.f;
            #pragma unroll 8
            for (int i = 0; i < D_; ++i)
                acc = fmaf(__shfl(m, i, 64), sW[i * D_ + lane], acc);
            states[((size_t)node * L_ + t) * D_ + lane] = tanhf(acc);
        }
    }
}

// ---------------- attention over L states + GRU update ----------------------
__global__ __launch_bounds__(256) void k_attn_gru(
    float* __restrict__ h, const float* __restrict__ states,
    const float* __restrict__ Wq, const float* __restrict__ Wk,
    const float* __restrict__ Wv, const float* __restrict__ Wo,
    const float* __restrict__ gWz, const float* __restrict__ gUz, const float* __restrict__ gbz,
    const float* __restrict__ gWr, const float* __restrict__ gUr, const float* __restrict__ gbr,
    const float* __restrict__ gWh, const float* __restrict__ gUh, const float* __restrict__ gbh)
{
    int wave = threadIdx.x >> 6;
    int lane = threadIdx.x & 63;
    int node = blockIdx.x * 4 + wave;

    float hval = h[(size_t)node * D_ + lane];
    float st0 = states[((size_t)node * L_ + 0) * D_ + lane];
    float st1 = states[((size_t)node * L_ + 1) * D_ + lane];
    float st2 = states[((size_t)node * L_ + 2) * D_ + lane];

    float q = 0.f, kk0 = 0.f, kk1 = 0.f, kk2 = 0.f, vv0 = 0.f, vv1 = 0.f, vv2 = 0.f;
    #pragma unroll 8
    for (int i = 0; i < D_; ++i) {
        float hi = __shfl(hval, i, 64);
        float s0 = __shfl(st0, i, 64), s1 = __shfl(st1, i, 64), s2 = __shfl(st2, i, 64);
        q = fmaf(hi, Wq[i * D_ + lane], q);
        float wk = Wk[i * D_ + lane];
        kk0 = fmaf(s0, wk, kk0); kk1 = fmaf(s1, wk, kk1); kk2 = fmaf(s2, wk, kk2);
        float wv = Wv[i * D_ + lane];
        vv0 = fmaf(s0, wv, vv0); vv1 = fmaf(s1, wv, vv1); vv2 = fmaf(s2, wv, vv2);
    }
    float p0 = q * kk0, p1 = q * kk1, p2 = q * kk2;
    #pragma unroll
    for (int m = 1; m < 16; m <<= 1) {
        p0 += __shfl_xor(p0, m, 64);
        p1 += __shfl_xor(p1, m, 64);
        p2 += __shfl_xor(p2, m, 64);
    }
    p0 *= 0.25f; p1 *= 0.25f; p2 *= 0.25f;   // / sqrt(dh=16)
    float mx = fmaxf(p0, fmaxf(p1, p2));
    float e0 = expf(p0 - mx), e1 = expf(p1 - mx), e2 = expf(p2 - mx);
    float inv = 1.f / (e0 + e1 + e2);
    float ao = (e0 * vv0 + e1 * vv1 + e2 * vv2) * inv;

    float xa = 0.f;
    #pragma unroll 8
    for (int i = 0; i < D_; ++i)
        xa = fmaf(__shfl(ao, i, 64), Wo[i * D_ + lane], xa);
    float x = tanhf(xa);

    float az = gbz[lane], ar = gbr[lane];
    #pragma unroll 8
    for (int i = 0; i < D_; ++i) {
        float xi = __shfl(x, i, 64), hi = __shfl(hval, i, 64);
        az = fmaf(xi, gWz[i * D_ + lane], az); az = fmaf(hi, gUz[i * D_ + lane], az);
        ar = fmaf(xi, gWr[i * D_ + lane], ar); ar = fmaf(hi, gUr[i * D_ + lane], ar);
    }
    float z = 1.f / (1.f + expf(-az));
    float r = 1.f / (1.f + expf(-ar));
    float rh = r * hval;

    float ah = gbh[lane];
    #pragma unroll 8
    for (int i = 0; i < D_; ++i) {
        ah = fmaf(__shfl(x, i, 64),  gWh[i * D_ + lane], ah);
        ah = fmaf(__shfl(rh, i, 64), gUh[i * D_ + lane], ah);
    }
    float hh = tanhf(ah);
    h[(size_t)node * D_ + lane] = (1.f - z) * hval + z * hh;
}

// ---------------- edge projection: P[node][0:32]=h@W1_top, [32:64]=h@W1_bot -
// one wave per node; lane<32 computes own-proj unit lane, lane>=32 nbr-proj
__global__ __launch_bounds__(256) void k_edgeproj(
    const float* __restrict__ h, const float* __restrict__ W1,
    float* __restrict__ P)
{
    int wave = threadIdx.x >> 6;
    int lane = threadIdx.x & 63;
    int node = blockIdx.x * 4 + wave;      // < 20000

    float hval = h[(size_t)node * D_ + lane];
    const float* wp = (lane < 32) ? (W1 + lane) : (W1 + 64 * 32 + (lane - 32));
    float acc = 0.f;
    #pragma unroll 8
    for (int i = 0; i < D_; ++i)
        acc = fmaf(__shfl(hval, i, 64), wp[i * 32], acc);
    P[(size_t)node * D_ + lane] = acc;
}

// ---------------- edge decoder (light): nw[e] -------------------------------
// half-wave per edge; per edge: 2 loads + tanh + 32-wide dot
__global__ __launch_bounds__(256) void k_decoder2(
    const float* __restrict__ P, const int* __restrict__ adj,
    const float* __restrict__ b1, const float* __restrict__ W2,
    const float* __restrict__ b2, const int* __restrict__ num_nodes,
    float* __restrict__ nw)
{
    int half = threadIdx.x >> 5;   // 0..7
    int j    = threadIdx.x & 31;
    float bias = b1[j], w2 = W2[j], b2v = b2[0];

    #pragma unroll 1
    for (int p = 0; p < 16; ++p) {
        int e = blockIdx.x * 128 + p * 8 + half;  // edge id < 320000
        int node = e >> 4;                        // b*N+n
        int b = node / N_;
        int a = adj[e];
        int pad = num_nodes[b];
        float own = P[(size_t)node * D_ + j];
        bool pd = (a == pad);
        float nbr = pd ? 0.f : P[((size_t)b * N_ + a) * D_ + 32 + j];
        float am = pd ? 0.f : 1.f;
        float t = tanhf(bias + am * own + nbr);
        float part = t * w2;
        #pragma unroll
        for (int m = 1; m < 32; m <<= 1) part += __shfl_xor(part, m, 64);
        if (j == 0) nw[e] = part + b2v;
    }
}

// ---------------- dual vars (per node scalar) + dual_demand -----------------
__global__ __launch_bounds__(256) void k_dualvars(
    const float* __restrict__ h, const float* __restrict__ W1,
    const float* __restrict__ b1, const float* __restrict__ W2,
    const float* __restrict__ b2, const float* __restrict__ demands,
    const int* __restrict__ num_nodes,
    float* __restrict__ dv, float* __restrict__ acc_out)
{
    __shared__ float sW1[D_ * 32];
    __shared__ float sW2[32];
    __shared__ float sPart[8];
    for (int i = threadIdx.x; i < D_ * 32; i += 256) sW1[i] = W1[i];
    if (threadIdx.x < 32) sW2[threadIdx.x] = W2[threadIdx.x];
    __syncthreads();

    int half = threadIdx.x >> 5;
    int j    = threadIdx.x & 31;
    int b = (blockIdx.x * 40) / N_;
    float bias = b1[j], b2v = b2[0];
    float local = 0.f;

    #pragma unroll 1
    for (int p = 0; p < 5; ++p) {
        int node = blockIdx.x * 40 + p * 8 + half;    // < 20000
        const float* hp = h + (size_t)node * D_;
        float h0 = hp[j], h1 = hp[j + 32];
        float acc = bias;
        #pragma unroll 8
        for (int i = 0; i < 32; ++i) {
            acc = fmaf(__shfl(h0, i, 32), sW1[i * 32 + j],        acc);
            acc = fmaf(__shfl(h1, i, 32), sW1[(i + 32) * 32 + j], acc);
        }
        float t = tanhf(acc);
        float part = t * sW2[j];
        #pragma unroll
        for (int m = 1; m < 32; m <<= 1) part += __shfl_xor(part, m, 64);
        if (j == 0) {
            float v = part + b2v;
            dv[node] = v;
            local += v * demands[node];
        }
    }
    if (j == 0) sPart[half] = local;
    __syncthreads();
    if (threadIdx.x == 0) {
        float s = 0.f;
        #pragma unroll
        for (int i = 0; i < 8; ++i) s += sPart[i];
        atomicAdd(&acc_out[(b * 3 + 2) * 16], s);
    }
}

// ---------------- dest softmax over permuted groups -------------------------
__global__ void k_dest(
    const float* __restrict__ nw, const int* __restrict__ in_idx,
    const int* __restrict__ inv_adj, const int* __restrict__ num_nodes,
    float* __restrict__ dest)
{
    int t = blockIdx.x * 256 + threadIdx.x;
    if (t >= BN_) return;
    int b = t / N_;
    int pad = num_nodes[b];
    float vals[K_]; float mx = -INFINITY;
    #pragma unroll
    for (int k = 0; k < K_; ++k) {
        int jj = in_idx[(size_t)t * K_ + k];
        float g = nw[(size_t)b * NK_ + jj];
        float im = (inv_adj[(size_t)t * K_ + k] == pad) ? 1.f : 0.f;
        float v = g - BIG_ * im;
        vals[k] = v; mx = fmaxf(mx, v);
    }
    float s = 0.f;
    #pragma unroll
    for (int k = 0; k < K_; ++k) { vals[k] = expf(vals[k] - mx); s += vals[k]; }
    float invs = 1.f / s;
    #pragma unroll
    for (int k = 0; k < K_; ++k) dest[(size_t)t * K_ + k] = vals[k] * invs;
}

// ---------------- normalized_weights + flow0 --------------------------------
__global__ void k_normw(
    const float* __restrict__ nw, const float* __restrict__ dest,
    const int* __restrict__ rev, const int* __restrict__ adj,
    const int* __restrict__ num_nodes, const float* __restrict__ demands,
    float* __restrict__ normw, float* __restrict__ flow0)
{
    int t = blockIdx.x * 256 + threadIdx.x;
    if (t >= BN_) return;
    int b = t / N_;
    int pad = num_nodes[b];
    float vals[K_]; float mx = -INFINITY;
    #pragma unroll
    for (int k = 0; k < K_; ++k) {
        size_t e = (size_t)t * K_ + k;
        float v = nw[e] * dest[(size_t)b * NK_ + rev[e]];
        float m = (adj[e] == pad) ? 1.f : 0.f;
        v -= BIG_ * m;
        vals[k] = v; mx = fmaxf(mx, v);
    }
    float s = 0.f;
    #pragma unroll
    for (int k = 0; k < K_; ++k) { vals[k] = expf(vals[k] - mx); s += vals[k]; }
    float invs = 1.f / s;
    float supply = fmaxf(-demands[t], 0.f);
    #pragma unroll
    for (int k = 0; k < K_; ++k) {
        float w = vals[k] * invs;
        normw[(size_t)t * K_ + k] = w;
        flow0[(size_t)t * K_ + k] = w * supply;
    }
}

// ---------------- one MCF flow step -----------------------------------------
__global__ void k_flow(
    const float* __restrict__ cur, const float* __restrict__ normw,
    const int* __restrict__ in_idx, const int* __restrict__ inv_adj,
    const int* __restrict__ num_nodes, const float* __restrict__ demands,
    float* __restrict__ nxt)
{
    int t = blockIdx.x * 256 + threadIdx.x;
    if (t >= BN_) return;
    int b = t / N_;
    int pad = num_nodes[b];
    float inflow = 0.f;
    #pragma unroll
    for (int k = 0; k < K_; ++k) {
        size_t e = (size_t)t * K_ + k;
        if (inv_adj[e] != pad) inflow += cur[(size_t)b * NK_ + in_idx[e]];
    }
    float tot = inflow + fmaxf(-demands[t], 0.f);
    #pragma unroll
    for (int k = 0; k < K_; ++k)
        nxt[(size_t)t * K_ + k] = normw[(size_t)t * K_ + k] * tot;
}

// ---------------- dual iterations + both cost reductions (dd fused) ---------
__global__ __launch_bounds__(256) void k_dualred(
    const float* __restrict__ el, const float* __restrict__ dv,
    const int* __restrict__ adj, const int* __restrict__ num_nodes,
    const float* __restrict__ flow, float* __restrict__ acc_out)
{
    int b = blockIdx.y;
    int ein = blockIdx.x * 256 + threadIdx.x;
    float c0 = 0.f, c1 = 0.f;
    if (ein < NK_) {
        size_t e = (size_t)b * NK_ + ein;
        int pad = num_nodes[b];
        int node = b * N_ + (ein >> 4);
        int a = adj[e];
        float am = (a == pad) ? 0.f : 1.f;
        float dtr = (a == pad) ? 0.f : dv[(size_t)b * N_ + a];
        float d = dtr - am * dv[node];
        float l = el[e];
        float f = 0.f, ac = 0.f;
        #pragma unroll
        for (int it = 0; it < 10; ++it) {
            float g = 2.f * l * f + d;
            ac = 0.9f * ac + 0.01f * g;
            f = fmaxf(f - ac, 0.f) * am;
        }
        float fl = flow[e];
        c0 = l * fl * fl;          // flow_cost term
        c1 = l * f * f + d * f;    // dual flow term
    }
    #pragma unroll
    for (int m = 1; m < 64; m <<= 1) { c0 += __shfl_xor(c0, m, 64); c1 += __shfl_xor(c1, m, 64); }
    __shared__ float s0[4], s1[4];
    int wave = threadIdx.x >> 6, lane = threadIdx.x & 63;
    if (lane == 0) { s0[wave] = c0; s1[wave] = c1; }
    __syncthreads();
    if (threadIdx.x == 0) {
        atomicAdd(&acc_out[(b * 3 + 0) * 16], s0[0] + s0[1] + s0[2] + s0[3]);
        atomicAdd(&acc_out[(b * 3 + 1) * 16], s1[0] + s1[1] + s1[2] + s1[3]);
    }
}

// ---------------- finalize --------------------------------------------------
__global__ void k_final(const float* __restrict__ acc, float* __restrict__ out) {
    int b = threadIdx.x;
    if (b < B_)
        out[b] = acc[(b * 3 + 0) * 16] - acc[(b * 3 + 1) * 16] + acc[(b * 3 + 2) * 16];
}

extern "C" void kernel_launch(void* const* d_in, const int* in_sizes, int n_in,
                              void* d_out, int out_size, void* d_ws, size_t ws_size,
                              hipStream_t stream)
{
    const float* demands = (const float*)d_in[0];
    const float* feat    = (const float*)d_in[1];
    const float* el      = (const float*)d_in[2];
    const float* embed   = (const float*)d_in[3];
    const float* encW    = (const float*)d_in[4];
    const float* encb    = (const float*)d_in[5];
    const float* nbW     = (const float*)d_in[6];
    const float* Wq      = (const float*)d_in[7];
    const float* Wk      = (const float*)d_in[8];
    const float* Wv      = (const float*)d_in[9];
    const float* Wo      = (const float*)d_in[10];
    const float* gWz     = (const float*)d_in[11];
    const float* gUz     = (const float*)d_in[12];
    const float* gbz     = (const float*)d_in[13];
    const float* gWr     = (const float*)d_in[14];
    const float* gUr     = (const float*)d_in[15];
    const float* gbr     = (const float*)d_in[16];
    const float* gWh     = (const float*)d_in[17];
    const float* gUh     = (const float*)d_in[18];
    const float* gbh     = (const float*)d_in[19];
    const float* decW1   = (const float*)d_in[20];
    const float* decb1   = (const float*)d_in[21];
    const float* decW2   = (const float*)d_in[22];
    const float* decb2   = (const float*)d_in[23];
    const float* dualW1  = (const float*)d_in[24];
    const float* dualb1  = (const float*)d_in[25];
    const float* dualW2  = (const float*)d_in[26];
    const float* dualb2  = (const float*)d_in[27];
    const int* adj       = (const int*)d_in[28];
    const int* invadj    = (const int*)d_in[29];
    const int* neigh     = (const int*)d_in[30];
    const int* inidx     = (const int*)d_in[31];
    const int* revidx    = (const int*)d_in[32];
    const int* numn      = (const int*)d_in[33];

    float* ws     = (float*)d_ws;
    float* h      = ws;                       // 1,280,000 f
    float* states = ws + 1280000;             // 3,840,000 f scratch region
    // region reuse after graph layers (all within states' 3.84M floats):
    float* nw     = states;                   // 320,000
    float* dest   = states + 320000;          // 320,000
    float* normw  = states + 640000;          // 320,000
    float* flowA  = states + 960000;          // 320,000
    float* flowB  = states + 1280000;         // 320,000
    float* dv     = states + 1600000;         // 20,000
    float* P      = states + 1620000;         // 1,280,000 (edge projections)
    float* acc    = ws + 5120000;             // 192 f (12 accumulators, 64B apart)

    k_zero<<<1, 256, 0, stream>>>(acc);
    k_encode<<<BN_ / 4, 256, 0, stream>>>(embed, feat, encW, encb, h);

    for (int layer = 0; layer < 2; ++layer) {
        k_agg<<<BN_ / 16, 256, 0, stream>>>(h, neigh, nbW, numn, states);
        k_attn_gru<<<BN_ / 4, 256, 0, stream>>>(h, states, Wq, Wk, Wv, Wo,
                                                gWz, gUz, gbz, gWr, gUr, gbr,
                                                gWh, gUh, gbh);
    }

    k_edgeproj<<<BN_ / 4, 256, 0, stream>>>(h, decW1, P);
    k_decoder2<<<(B_ * NK_) / 128, 256, 0, stream>>>(P, adj, decb1, decW2, decb2, numn, nw);
    k_dualvars<<<BN_ / 40, 256, 0, stream>>>(h, dualW1, dualb1, dualW2, dualb2, demands, numn, dv, acc);
    k_dest<<<(BN_ + 255) / 256, 256, 0, stream>>>(nw, inidx, invadj, numn, dest);
    k_normw<<<(BN_ + 255) / 256, 256, 0, stream>>>(nw, dest, revidx, adj, numn, demands, normw, flowA);

    float* cur = flowA; float* nxt = flowB;
    for (int it = 0; it < 10; ++it) {
        k_flow<<<(BN_ + 255) / 256, 256, 0, stream>>>(cur, normw, inidx, invadj, numn, demands, nxt);
        float* tmp = cur; cur = nxt; nxt = tmp;
    }

    dim3 gred((NK_ + 255) / 256, B_);
    k_dualred<<<gred, 256, 0, stream>>>(el, dv, adj, numn, cur, acc);
    k_final<<<1, 64, 0, stream>>>(acc, (float*)d_out);
}

// Round 4
// 716.860 us; speedup vs baseline: 1.3979x; 1.0011x over previous
//
#include <hip/hip_runtime.h>
#include <math.h>

#define B_ 4
#define N_ 5000
#define K_ 16
#define L_ 3
#define F_ 2
#define E_ 32
#define D_ 64
#define H_ 4
#define BN_ (B_*N_)          /* 20000 */
#define NK_ (N_*K_)          /* 80000 */
#define BIG_ 1.0e9f

// ---------------- zero the accumulators -------------------------------------
__global__ void k_zero(float* __restrict__ acc) {
    if (threadIdx.x < 192) acc[threadIdx.x] = 0.f;
}

// ---------------- encoder: h = [emb_norm, feat] @ enc_W + enc_b -------------
__global__ __launch_bounds__(256) void k_encode(
    const float* __restrict__ embed, const float* __restrict__ feat,
    const float* __restrict__ encW, const float* __restrict__ encb,
    float* __restrict__ h)
{
    int wave = threadIdx.x >> 6;
    int lane = threadIdx.x & 63;
    int node = blockIdx.x * 4 + wave;      // b*N+n  in [0,20000)
    int n = node % N_;

    float e = (lane < E_) ? embed[(size_t)n * E_ + lane] : 0.f;
    float ss = e * e;
    #pragma unroll
    for (int m = 32; m >= 1; m >>= 1) ss += __shfl_xor(ss, m, 64);
    float scale = 1.f / fmaxf(sqrtf(ss), 1.f);

    float inval = (lane < E_) ? e * scale
                : (lane < E_ + F_) ? feat[(size_t)node * F_ + (lane - E_)]
                : 0.f;

    float acc = encb[lane];
    #pragma unroll
    for (int i = 0; i < E_ + F_; ++i)
        acc = fmaf(__shfl(inval, i, 64), encW[i * D_ + lane], acc);
    h[(size_t)node * D_ + lane] = acc;
}

// ---------------- gather + mean over neighborhoods (no matmul) --------------
// mean layout: [t*BN + node][64]
__global__ __launch_bounds__(256) void k_aggmean(
    const float* __restrict__ h, const int* __restrict__ neigh,
    const int* __restrict__ num_nodes, float* __restrict__ mean)
{
    int wave = threadIdx.x >> 6;
    int lane = threadIdx.x & 63;
    int node = blockIdx.x * 4 + wave;      // b*N+n
    int b = node / N_;
    int pad = num_nodes[b];
    const float* hb = h + (size_t)b * N_ * D_;

    for (int t = 0; t < L_; ++t) {
        const int* nb = neigh + ((size_t)t * BN_ + node) * K_;
        float sum = 0.f; int cnt = 0;
        #pragma unroll
        for (int k = 0; k < K_; ++k) {
            int idx = nb[k];
            if (idx != pad) { sum += hb[(size_t)idx * D_ + lane]; cnt++; }
        }
        mean[((size_t)t * BN_ + node) * D_ + lane] = sum / fmaxf((float)cnt, 1.f);
    }
}

// ================= tiled f32 GEMM core: 64 rows x 64 cols per block =========
// thread (tx): cols c0..c0+3 (c0=(tx&15)*4), rows r0..r0+3 (r0=bid*64+(tx>>4)*4)
// W staged in LDS (16KB), A streamed as float4 (L1-broadcast across col groups)
// In-place C=A is SAFE: each thread reads only its own rows (guarded OOB),
// row-sharing threads are within one wave (lockstep), writes after all reads.

// ---- single-W GEMM, ACT: 0=none, 1=tanh -----------------------------------
template<int ACT>
__global__ __launch_bounds__(256) void g_mm(
    const float* A, const float* __restrict__ W, float* C, int M)
{
    __shared__ float sW[4096];
    int tx = threadIdx.x;
    #pragma unroll
    for (int idx = tx; idx < 1024; idx += 256)
        ((float4*)sW)[idx] = ((const float4*)W)[idx];
    __syncthreads();

    int c0 = (tx & 15) * 4;
    int r0 = blockIdx.x * 64 + (tx >> 4) * 4;
    bool ok[4]; size_t ro[4];
    #pragma unroll
    for (int k = 0; k < 4; ++k) { ok[k] = (r0 + k) < M; ro[k] = (size_t)(r0 + k) * 64; }

    float acc[4][4] = {};
    for (int i = 0; i < 64; i += 4) {
        float va[4][4];
        #pragma unroll
        for (int k = 0; k < 4; ++k) {
            float4 t = ok[k] ? *(const float4*)(A + ro[k] + i)
                             : make_float4(0.f, 0.f, 0.f, 0.f);
            va[k][0] = t.x; va[k][1] = t.y; va[k][2] = t.z; va[k][3] = t.w;
        }
        #pragma unroll
        for (int ii = 0; ii < 4; ++ii) {
            float4 w = *(const float4*)&sW[(i + ii) * 64 + c0];
            #pragma unroll
            for (int k = 0; k < 4; ++k) {
                float av = va[k][ii];
                acc[k][0] = fmaf(av, w.x, acc[k][0]);
                acc[k][1] = fmaf(av, w.y, acc[k][1]);
                acc[k][2] = fmaf(av, w.z, acc[k][2]);
                acc[k][3] = fmaf(av, w.w, acc[k][3]);
            }
        }
    }
    #pragma unroll
    for (int k = 0; k < 4; ++k) {
        if (!ok[k]) continue;
        float4 o;
        o.x = (ACT == 1) ? tanhf(acc[k][0]) : acc[k][0];
        o.y = (ACT == 1) ? tanhf(acc[k][1]) : acc[k][1];
        o.z = (ACT == 1) ? tanhf(acc[k][2]) : acc[k][2];
        o.w = (ACT == 1) ? tanhf(acc[k][3]) : acc[k][3];
        *(float4*)(C + ro[k] + c0) = o;
    }
}

// ---- dual-W GEMM: Ck = A@Wk (may alias A), Cv = A@Wv -----------------------
__global__ __launch_bounds__(256) void g_kv(
    const float* A, const float* __restrict__ Wk, const float* __restrict__ Wv,
    float* Ck, float* Cv, int M)
{
    __shared__ float sWk[4096], sWv[4096];
    int tx = threadIdx.x;
    #pragma unroll
    for (int idx = tx; idx < 1024; idx += 256) {
        ((float4*)sWk)[idx] = ((const float4*)Wk)[idx];
        ((float4*)sWv)[idx] = ((const float4*)Wv)[idx];
    }
    __syncthreads();

    int c0 = (tx & 15) * 4;
    int r0 = blockIdx.x * 64 + (tx >> 4) * 4;
    bool ok[4]; size_t ro[4];
    #pragma unroll
    for (int k = 0; k < 4; ++k) { ok[k] = (r0 + k) < M; ro[k] = (size_t)(r0 + k) * 64; }

    float ak[4][4] = {}, av2[4][4] = {};
    for (int i = 0; i < 64; i += 4) {
        float va[4][4];
        #pragma unroll
        for (int k = 0; k < 4; ++k) {
            float4 t = ok[k] ? *(const float4*)(A + ro[k] + i)
                             : make_float4(0.f, 0.f, 0.f, 0.f);
            va[k][0] = t.x; va[k][1] = t.y; va[k][2] = t.z; va[k][3] = t.w;
        }
        #pragma unroll
        for (int ii = 0; ii < 4; ++ii) {
            float4 wk = *(const float4*)&sWk[(i + ii) * 64 + c0];
            float4 wv = *(const float4*)&sWv[(i + ii) * 64 + c0];
            #pragma unroll
            for (int k = 0; k < 4; ++k) {
                float a = va[k][ii];
                ak[k][0] = fmaf(a, wk.x, ak[k][0]);
                ak[k][1] = fmaf(a, wk.y, ak[k][1]);
                ak[k][2] = fmaf(a, wk.z, ak[k][2]);
                ak[k][3] = fmaf(a, wk.w, ak[k][3]);
                av2[k][0] = fmaf(a, wv.x, av2[k][0]);
                av2[k][1] = fmaf(a, wv.y, av2[k][1]);
                av2[k][2] = fmaf(a, wv.z, av2[k][2]);
                av2[k][3] = fmaf(a, wv.w, av2[k][3]);
            }
        }
    }
    #pragma unroll
    for (int k = 0; k < 4; ++k) {
        if (!ok[k]) continue;
        *(float4*)(Ck + ro[k] + c0) = make_float4(ak[k][0], ak[k][1], ak[k][2], ak[k][3]);
        *(float4*)(Cv + ro[k] + c0) = make_float4(av2[k][0], av2[k][1], av2[k][2], av2[k][3]);
    }
}

// ---- GRU z/r: z=sig(x@Wz+h@Uz+bz), r=sig(x@Wr+h@Ur+br), RH=r*h -------------
__global__ __launch_bounds__(256) void g_zr(
    const float* __restrict__ X, const float* __restrict__ Hin,
    const float* __restrict__ Wz, const float* __restrict__ Uz, const float* __restrict__ bz,
    const float* __restrict__ Wr, const float* __restrict__ Ur, const float* __restrict__ br,
    float* __restrict__ Z, float* __restrict__ RH, int M)
{
    __shared__ float sWz[4096], sUz[4096], sWr[4096], sUr[4096];  // 64KB
    int tx = threadIdx.x;
    #pragma unroll
    for (int idx = tx; idx < 1024; idx += 256) {
        ((float4*)sWz)[idx] = ((const float4*)Wz)[idx];
        ((float4*)sUz)[idx] = ((const float4*)Uz)[idx];
        ((float4*)sWr)[idx] = ((const float4*)Wr)[idx];
        ((float4*)sUr)[idx] = ((const float4*)Ur)[idx];
    }
    __syncthreads();

    int c0 = (tx & 15) * 4;
    int r0 = blockIdx.x * 64 + (tx >> 4) * 4;
    bool ok[4]; size_t ro[4];
    #pragma unroll
    for (int k = 0; k < 4; ++k) { ok[k] = (r0 + k) < M; ro[k] = (size_t)(r0 + k) * 64; }

    float az[4][4] = {}, ar[4][4] = {};
    for (int i = 0; i < 64; i += 4) {
        float vx[4][4], vh[4][4];
        #pragma unroll
        for (int k = 0; k < 4; ++k) {
            float4 t = ok[k] ? *(const float4*)(X + ro[k] + i)
                             : make_float4(0.f, 0.f, 0.f, 0.f);
            vx[k][0] = t.x; vx[k][1] = t.y; vx[k][2] = t.z; vx[k][3] = t.w;
            float4 u = ok[k] ? *(const float4*)(Hin + ro[k] + i)
                             : make_float4(0.f, 0.f, 0.f, 0.f);
            vh[k][0] = u.x; vh[k][1] = u.y; vh[k][2] = u.z; vh[k][3] = u.w;
        }
        #pragma unroll
        for (int ii = 0; ii < 4; ++ii) {
            float4 wz = *(const float4*)&sWz[(i + ii) * 64 + c0];
            float4 uz = *(const float4*)&sUz[(i + ii) * 64 + c0];
            float4 wr = *(const float4*)&sWr[(i + ii) * 64 + c0];
            float4 ur = *(const float4*)&sUr[(i + ii) * 64 + c0];
            #pragma unroll
            for (int k = 0; k < 4; ++k) {
                float xv = vx[k][ii], hv = vh[k][ii];
                az[k][0] = fmaf(xv, wz.x, fmaf(hv, uz.x, az[k][0]));
                az[k][1] = fmaf(xv, wz.y, fmaf(hv, uz.y, az[k][1]));
                az[k][2] = fmaf(xv, wz.z, fmaf(hv, uz.z, az[k][2]));
                az[k][3] = fmaf(xv, wz.w, fmaf(hv, uz.w, az[k][3]));
                ar[k][0] = fmaf(xv, wr.x, fmaf(hv, ur.x, ar[k][0]));
                ar[k][1] = fmaf(xv, wr.y, fmaf(hv, ur.y, ar[k][1]));
                ar[k][2] = fmaf(xv, wr.z, fmaf(hv, ur.z, ar[k][2]));
                ar[k][3] = fmaf(xv, wr.w, fmaf(hv, ur.w, ar[k][3]));
            }
        }
    }
    float4 bzv = *(const float4*)(bz + c0);
    float4 brv = *(const float4*)(br + c0);
    #pragma unroll
    for (int k = 0; k < 4; ++k) {
        if (!ok[k]) continue;
        float4 hv = *(const float4*)(Hin + ro[k] + c0);
        float z0 = 1.f / (1.f + expf(-(az[k][0] + bzv.x)));
        float z1 = 1.f / (1.f + expf(-(az[k][1] + bzv.y)));
        float z2 = 1.f / (1.f + expf(-(az[k][2] + bzv.z)));
        float z3 = 1.f / (1.f + expf(-(az[k][3] + bzv.w)));
        float r0v = 1.f / (1.f + expf(-(ar[k][0] + brv.x)));
        float r1v = 1.f / (1.f + expf(-(ar[k][1] + brv.y)));
        float r2v = 1.f / (1.f + expf(-(ar[k][2] + brv.z)));
        float r3v = 1.f / (1.f + expf(-(ar[k][3] + brv.w)));
        *(float4*)(Z + ro[k] + c0)  = make_float4(z0, z1, z2, z3);
        *(float4*)(RH + ro[k] + c0) = make_float4(r0v * hv.x, r1v * hv.y, r2v * hv.z, r3v * hv.w);
    }
}

// ---- GRU final: H = (1-z)*H + z*tanh(x@Wh + rh@Uh + bh)  (in-place H) ------
__global__ __launch_bounds__(256) void g_hfin(
    const float* __restrict__ X, const float* __restrict__ RH,
    const float* __restrict__ Wh, const float* __restrict__ Uh, const float* __restrict__ bh,
    const float* __restrict__ Z, float* Hio, int M)
{
    __shared__ float sWh[4096], sUh[4096];
    int tx = threadIdx.x;
    #pragma unroll
    for (int idx = tx; idx < 1024; idx += 256) {
        ((float4*)sWh)[idx] = ((const float4*)Wh)[idx];
        ((float4*)sUh)[idx] = ((const float4*)Uh)[idx];
    }
    __syncthreads();

    int c0 = (tx & 15) * 4;
    int r0 = blockIdx.x * 64 + (tx >> 4) * 4;
    bool ok[4]; size_t ro[4];
    #pragma unroll
    for (int k = 0; k < 4; ++k) { ok[k] = (r0 + k) < M; ro[k] = (size_t)(r0 + k) * 64; }

    float acc[4][4] = {};
    for (int i = 0; i < 64; i += 4) {
        float vx[4][4], vr[4][4];
        #pragma unroll
        for (int k = 0; k < 4; ++k) {
            float4 t = ok[k] ? *(const float4*)(X + ro[k] + i)
                             : make_float4(0.f, 0.f, 0.f, 0.f);
            vx[k][0] = t.x; vx[k][1] = t.y; vx[k][2] = t.z; vx[k][3] = t.w;
            float4 u = ok[k] ? *(const float4*)(RH + ro[k] + i)
                             : make_float4(0.f, 0.f, 0.f, 0.f);
            vr[k][0] = u.x; vr[k][1] = u.y; vr[k][2] = u.z; vr[k][3] = u.w;
        }
        #pragma unroll
        for (int ii = 0; ii < 4; ++ii) {
            float4 wh = *(const float4*)&sWh[(i + ii) * 64 + c0];
            float4 uh = *(const float4*)&sUh[(i + ii) * 64 + c0];
            #pragma unroll
            for (int k = 0; k < 4; ++k) {
                float xv = vx[k][ii], rv = vr[k][ii];
                acc[k][0] = fmaf(xv, wh.x, fmaf(rv, uh.x, acc[k][0]));
                acc[k][1] = fmaf(xv, wh.y, fmaf(rv, uh.y, acc[k][1]));
                acc[k][2] = fmaf(xv, wh.z, fmaf(rv, uh.z, acc[k][2]));
                acc[k][3] = fmaf(xv, wh.w, fmaf(rv, uh.w, acc[k][3]));
            }
        }
    }
    float4 bhv = *(const float4*)(bh + c0);
    #pragma unroll
    for (int k = 0; k < 4; ++k) {
        if (!ok[k]) continue;
        float4 zv = *(const float4*)(Z + ro[k] + c0);
        float4 hv = *(const float4*)(Hio + ro[k] + c0);
        float h0 = (1.f - zv.x) * hv.x + zv.x * tanhf(acc[k][0] + bhv.x);
        float h1 = (1.f - zv.y) * hv.y + zv.y * tanhf(acc[k][1] + bhv.y);
        float h2 = (1.f - zv.z) * hv.z + zv.z * tanhf(acc[k][2] + bhv.z);
        float h3 = (1.f - zv.w) * hv.w + zv.w * tanhf(acc[k][3] + bhv.w);
        *(float4*)(Hio + ro[k] + c0) = make_float4(h0, h1, h2, h3);
    }
}

// ---------------- attention elementwise: ao from q,kk,vv (ao aliases q) -----
__global__ __launch_bounds__(256) void k_attn2(
    float* q, const float* kk, const float* vv)
{
    int wave = threadIdx.x >> 6;
    int lane = threadIdx.x & 63;
    int node = blockIdx.x * 4 + wave;

    float qv = q[(size_t)node * D_ + lane];
    float k0 = kk[((size_t)0 * BN_ + node) * D_ + lane];
    float k1 = kk[((size_t)1 * BN_ + node) * D_ + lane];
    float k2 = kk[((size_t)2 * BN_ + node) * D_ + lane];
    float v0 = vv[((size_t)0 * BN_ + node) * D_ + lane];
    float v1 = vv[((size_t)1 * BN_ + node) * D_ + lane];
    float v2 = vv[((size_t)2 * BN_ + node) * D_ + lane];

    float p0 = qv * k0, p1 = qv * k1, p2 = qv * k2;
    #pragma unroll
    for (int m = 1; m < 16; m <<= 1) {
        p0 += __shfl_xor(p0, m, 64);
        p1 += __shfl_xor(p1, m, 64);
        p2 += __shfl_xor(p2, m, 64);
    }
    p0 *= 0.25f; p1 *= 0.25f; p2 *= 0.25f;   // / sqrt(dh=16)
    float mx = fmaxf(p0, fmaxf(p1, p2));
    float e0 = expf(p0 - mx), e1 = expf(p1 - mx), e2 = expf(p2 - mx);
    float inv = 1.f / (e0 + e1 + e2);
    q[(size_t)node * D_ + lane] = (e0 * v0 + e1 * v1 + e2 * v2) * inv;
}

// ---------------- edge projection ------------------------------------------
__global__ __launch_bounds__(256) void k_edgeproj(
    const float* __restrict__ h, const float* __restrict__ W1,
    float* __restrict__ P)
{
    int wave = threadIdx.x >> 6;
    int lane = threadIdx.x & 63;
    int node = blockIdx.x * 4 + wave;      // < 20000

    float hval = h[(size_t)node * D_ + lane];
    const float* wp = (lane < 32) ? (W1 + lane) : (W1 + 64 * 32 + (lane - 32));
    float acc = 0.f;
    #pragma unroll 8
    for (int i = 0; i < D_; ++i)
        acc = fmaf(__shfl(hval, i, 64), wp[i * 32], acc);
    P[(size_t)node * D_ + lane] = acc;
}

// ---------------- edge decoder (light) --------------------------------------
__global__ __launch_bounds__(256) void k_decoder2(
    const float* __restrict__ P, const int* __restrict__ adj,
    const float* __restrict__ b1, const float* __restrict__ W2,
    const float* __restrict__ b2, const int* __restrict__ num_nodes,
    float* __restrict__ nw)
{
    int half = threadIdx.x >> 5;   // 0..7
    int j    = threadIdx.x & 31;
    float bias = b1[j], w2 = W2[j], b2v = b2[0];

    #pragma unroll 1
    for (int p = 0; p < 16; ++p) {
        int e = blockIdx.x * 128 + p * 8 + half;  // edge id < 320000
        int node = e >> 4;                        // b*N+n
        int b = node / N_;
        int a = adj[e];
        int pad = num_nodes[b];
        float own = P[(size_t)node * D_ + j];
        bool pd = (a == pad);
        float nbr = pd ? 0.f : P[((size_t)b * N_ + a) * D_ + 32 + j];
        float am = pd ? 0.f : 1.f;
        float t = tanhf(bias + am * own + nbr);
        float part = t * w2;
        #pragma unroll
        for (int m = 1; m < 32; m <<= 1) part += __shfl_xor(part, m, 64);
        if (j == 0) nw[e] = part + b2v;
    }
}

// ---------------- dual vars (per node scalar) + dual_demand -----------------
__global__ __launch_bounds__(256) void k_dualvars(
    const float* __restrict__ h, const float* __restrict__ W1,
    const float* __restrict__ b1, const float* __restrict__ W2,
    const float* __restrict__ b2, const float* __restrict__ demands,
    const int* __restrict__ num_nodes,
    float* __restrict__ dv, float* __restrict__ acc_out)
{
    __shared__ float sW1[D_ * 32];
    __shared__ float sW2[32];
    __shared__ float sPart[8];
    for (int i = threadIdx.x; i < D_ * 32; i += 256) sW1[i] = W1[i];
    if (threadIdx.x < 32) sW2[threadIdx.x] = W2[threadIdx.x];
    __syncthreads();

    int half = threadIdx.x >> 5;
    int j    = threadIdx.x & 31;
    int b = (blockIdx.x * 40) / N_;
    float bias = b1[j], b2v = b2[0];
    float local = 0.f;

    #pragma unroll 1
    for (int p = 0; p < 5; ++p) {
        int node = blockIdx.x * 40 + p * 8 + half;    // < 20000
        const float* hp = h + (size_t)node * D_;
        float h0 = hp[j], h1 = hp[j + 32];
        float acc = bias;
        #pragma unroll 8
        for (int i = 0; i < 32; ++i) {
            acc = fmaf(__shfl(h0, i, 32), sW1[i * 32 + j],        acc);
            acc = fmaf(__shfl(h1, i, 32), sW1[(i + 32) * 32 + j], acc);
        }
        float t = tanhf(acc);
        float part = t * sW2[j];
        #pragma unroll
        for (int m = 1; m < 32; m <<= 1) part += __shfl_xor(part, m, 64);
        if (j == 0) {
            float v = part + b2v;
            dv[node] = v;
            local += v * demands[node];
        }
    }
    if (j == 0) sPart[half] = local;
    __syncthreads();
    if (threadIdx.x == 0) {
        float s = 0.f;
        #pragma unroll
        for (int i = 0; i < 8; ++i) s += sPart[i];
        atomicAdd(&acc_out[(b * 3 + 2) * 16], s);
    }
}

// ---------------- dest softmax over permuted groups -------------------------
__global__ void k_dest(
    const float* __restrict__ nw, const int* __restrict__ in_idx,
    const int* __restrict__ inv_adj, const int* __restrict__ num_nodes,
    float* __restrict__ dest)
{
    int t = blockIdx.x * 256 + threadIdx.x;
    if (t >= BN_) return;
    int b = t / N_;
    int pad = num_nodes[b];
    float vals[K_]; float mx = -INFINITY;
    #pragma unroll
    for (int k = 0; k < K_; ++k) {
        int jj = in_idx[(size_t)t * K_ + k];
        float g = nw[(size_t)b * NK_ + jj];
        float im = (inv_adj[(size_t)t * K_ + k] == pad) ? 1.f : 0.f;
        float v = g - BIG_ * im;
        vals[k] = v; mx = fmaxf(mx, v);
    }
    float s = 0.f;
    #pragma unroll
    for (int k = 0; k < K_; ++k) { vals[k] = expf(vals[k] - mx); s += vals[k]; }
    float invs = 1.f / s;
    #pragma unroll
    for (int k = 0; k < K_; ++k) dest[(size_t)t * K_ + k] = vals[k] * invs;
}

// ---------------- normalized_weights + flow0 --------------------------------
__global__ void k_normw(
    const float* __restrict__ nw, const float* __restrict__ dest,
    const int* __restrict__ rev, const int* __restrict__ adj,
    const int* __restrict__ num_nodes, const float* __restrict__ demands,
    float* __restrict__ normw, float* __restrict__ flow0)
{
    int t = blockIdx.x * 256 + threadIdx.x;
    if (t >= BN_) return;
    int b = t / N_;
    int pad = num_nodes[b];
    float vals[K_]; float mx = -INFINITY;
    #pragma unroll
    for (int k = 0; k < K_; ++k) {
        size_t e = (size_t)t * K_ + k;
        float v = nw[e] * dest[(size_t)b * NK_ + rev[e]];
        float m = (adj[e] == pad) ? 1.f : 0.f;
        v -= BIG_ * m;
        vals[k] = v; mx = fmaxf(mx, v);
    }
    float s = 0.f;
    #pragma unroll
    for (int k = 0; k < K_; ++k) { vals[k] = expf(vals[k] - mx); s += vals[k]; }
    float invs = 1.f / s;
    float supply = fmaxf(-demands[t], 0.f);
    #pragma unroll
    for (int k = 0; k < K_; ++k) {
        float w = vals[k] * invs;
        normw[(size_t)t * K_ + k] = w;
        flow0[(size_t)t * K_ + k] = w * supply;
    }
}

// ---------------- one MCF flow step -----------------------------------------
__global__ void k_flow(
    const float* __restrict__ cur, const float* __restrict__ normw,
    const int* __restrict__ in_idx, const int* __restrict__ inv_adj,
    const int* __restrict__ num_nodes, const float* __restrict__ demands,
    float* __restrict__ nxt)
{
    int t = blockIdx.x * 256 + threadIdx.x;
    if (t >= BN_) return;
    int b = t / N_;
    int pad = num_nodes[b];
    float inflow = 0.f;
    #pragma unroll
    for (int k = 0; k < K_; ++k) {
        size_t e = (size_t)t * K_ + k;
        if (inv_adj[e] != pad) inflow += cur[(size_t)b * NK_ + in_idx[e]];
    }
    float tot = inflow + fmaxf(-demands[t], 0.f);
    #pragma unroll
    for (int k = 0; k < K_; ++k)
        nxt[(size_t)t * K_ + k] = normw[(size_t)t * K_ + k] * tot;
}

// ---------------- dual iterations + both cost reductions (dd fused) ---------
__global__ __launch_bounds__(256) void k_dualred(
    const float* __restrict__ el, const float* __restrict__ dv,
    const int* __restrict__ adj, const int* __restrict__ num_nodes,
    const float* __restrict__ flow, float* __restrict__ acc_out)
{
    int b = blockIdx.y;
    int ein = blockIdx.x * 256 + threadIdx.x;
    float c0 = 0.f, c1 = 0.f;
    if (ein < NK_) {
        size_t e = (size_t)b * NK_ + ein;
        int pad = num_nodes[b];
        int node = b * N_ + (ein >> 4);
        int a = adj[e];
        float am = (a == pad) ? 0.f : 1.f;
        float dtr = (a == pad) ? 0.f : dv[(size_t)b * N_ + a];
        float d = dtr - am * dv[node];
        float l = el[e];
        float f = 0.f, ac = 0.f;
        #pragma unroll
        for (int it = 0; it < 10; ++it) {
            float g = 2.f * l * f + d;
            ac = 0.9f * ac + 0.01f * g;
            f = fmaxf(f - ac, 0.f) * am;
        }
        float fl = flow[e];
        c0 = l * fl * fl;          // flow_cost term
        c1 = l * f * f + d * f;    // dual flow term
    }
    #pragma unroll
    for (int m = 1; m < 64; m <<= 1) { c0 += __shfl_xor(c0, m, 64); c1 += __shfl_xor(c1, m, 64); }
    __shared__ float s0[4], s1[4];
    int wave = threadIdx.x >> 6, lane = threadIdx.x & 63;
    if (lane == 0) { s0[wave] = c0; s1[wave] = c1; }
    __syncthreads();
    if (threadIdx.x == 0) {
        atomicAdd(&acc_out[(b * 3 + 0) * 16], s0[0] + s0[1] + s0[2] + s0[3]);
        atomicAdd(&acc_out[(b * 3 + 1) * 16], s1[0] + s1[1] + s1[2] + s1[3]);
    }
}

// ---------------- finalize --------------------------------------------------
__global__ void k_final(const float* __restrict__ acc, float* __restrict__ out) {
    int b = threadIdx.x;
    if (b < B_)
        out[b] = acc[(b * 3 + 0) * 16] - acc[(b * 3 + 1) * 16] + acc[(b * 3 + 2) * 16];
}

extern "C" void kernel_launch(void* const* d_in, const int* in_sizes, int n_in,
                              void* d_out, int out_size, void* d_ws, size_t ws_size,
                              hipStream_t stream)
{
    const float* demands = (const float*)d_in[0];
    const float* feat    = (const float*)d_in[1];
    const float* el      = (const float*)d_in[2];
    const float* embed   = (const float*)d_in[3];
    const float* encW    = (const float*)d_in[4];
    const float* encb    = (const float*)d_in[5];
    const float* nbW     = (const float*)d_in[6];
    const float* Wq      = (const float*)d_in[7];
    const float* Wk      = (const float*)d_in[8];
    const float* Wv      = (const float*)d_in[9];
    const float* Wo      = (const float*)d_in[10];
    const float* gWz     = (const float*)d_in[11];
    const float* gUz     = (const float*)d_in[12];
    const float* gbz     = (const float*)d_in[13];
    const float* gWr     = (const float*)d_in[14];
    const float* gUr     = (const float*)d_in[15];
    const float* gbr     = (const float*)d_in[16];
    const float* gWh     = (const float*)d_in[17];
    const float* gUh     = (const float*)d_in[18];
    const float* gbh     = (const float*)d_in[19];
    const float* decW1   = (const float*)d_in[20];
    const float* decb1   = (const float*)d_in[21];
    const float* decW2   = (const float*)d_in[22];
    const float* decb2   = (const float*)d_in[23];
    const float* dualW1  = (const float*)d_in[24];
    const float* dualb1  = (const float*)d_in[25];
    const float* dualW2  = (const float*)d_in[26];
    const float* dualb2  = (const float*)d_in[27];
    const int* adj       = (const int*)d_in[28];
    const int* invadj    = (const int*)d_in[29];
    const int* neigh     = (const int*)d_in[30];
    const int* inidx     = (const int*)d_in[31];
    const int* revidx    = (const int*)d_in[32];
    const int* numn      = (const int*)d_in[33];

    // workspace layout (floats), total 10,240,192 f = 40.96 MB
    float* ws   = (float*)d_ws;
    float* h    = ws;                   // 1,280,000        (h, in-place updated)
    float* sbuf = ws + 1280000;         // 3,840,000        (mean -> states -> kk)
    float* vvb  = ws + 5120000;         // 3,840,000        (vv; then z, rh)
    float* q    = ws + 8960000;         // 1,280,000        (q -> ao -> x; then P)
    float* acc  = ws + 10240000;        // 192

    float* zbuf = vvb;                  // 1,280,000 (after attn, vv dead)
    float* rhb  = vvb + 1280000;        // 1,280,000
    // flow-phase aliases (sbuf + q regions, all dead after layers)
    float* nw    = sbuf;                // 320,000
    float* dest  = sbuf + 320000;       // 320,000
    float* normw = sbuf + 640000;       // 320,000
    float* flowA = sbuf + 960000;       // 320,000
    float* flowB = sbuf + 1280000;      // 320,000
    float* dv    = sbuf + 1600000;      // 20,000
    float* P     = q;                   // 1,280,000

    const int GB20 = (BN_ + 63) / 64;       // 313
    const int GB60 = (3 * BN_ + 63) / 64;   // 938

    k_zero<<<1, 256, 0, stream>>>(acc);
    k_encode<<<BN_ / 4, 256, 0, stream>>>(embed, feat, encW, encb, h);

    for (int layer = 0; layer < 2; ++layer) {
        k_aggmean<<<BN_ / 4, 256, 0, stream>>>(h, neigh, numn, sbuf);
        g_mm<1><<<GB60, 256, 0, stream>>>(sbuf, nbW, sbuf, 3 * BN_);          // states (in-place)
        g_mm<0><<<GB20, 256, 0, stream>>>(h, Wq, q, BN_);                     // q
        g_kv<<<GB60, 256, 0, stream>>>(sbuf, Wk, Wv, sbuf, vvb, 3 * BN_);     // kk (in-place), vv
        k_attn2<<<BN_ / 4, 256, 0, stream>>>(q, sbuf, vvb);                   // ao (in-place q)
        g_mm<1><<<GB20, 256, 0, stream>>>(q, Wo, q, BN_);                     // x = tanh(ao@Wo)
        g_zr<<<GB20, 256, 0, stream>>>(q, h, gWz, gUz, gbz, gWr, gUr, gbr,
                                       zbuf, rhb, BN_);                       // z, rh
        g_hfin<<<GB20, 256, 0, stream>>>(q, rhb, gWh, gUh, gbh, zbuf, h, BN_);// h' (in-place)
    }

    k_edgeproj<<<BN_ / 4, 256, 0, stream>>>(h, decW1, P);
    k_decoder2<<<(B_ * NK_) / 128, 256, 0, stream>>>(P, adj, decb1, decW2, decb2, numn, nw);
    k_dualvars<<<BN_ / 40, 256, 0, stream>>>(h, dualW1, dualb1, dualW2, dualb2, demands, numn, dv, acc);
    k_dest<<<(BN_ + 255) / 256, 256, 0, stream>>>(nw, inidx, invadj, numn, dest);
    k_normw<<<(BN_ + 255) / 256, 256, 0, stream>>>(nw, dest, revidx, adj, numn, demands, normw, flowA);

    float* cur = flowA; float* nxt = flowB;
    for (int it = 0; it < 10; ++it) {
        k_flow<<<(BN_ + 255) / 256, 256, 0, stream>>>(cur, normw, inidx, invadj, numn, demands, nxt);
        float* tmp = cur; cur = nxt; nxt = tmp;
    }

    dim3 gred((NK_ + 255) / 256, B_);
    k_dualred<<<gred, 256, 0, stream>>>(el, dv, adj, numn, cur, acc);
    k_final<<<1, 64, 0, stream>>>(acc, (float*)d_out);
}